// Round 12
// baseline (626.296 us; speedup 1.0000x reference)
//
#include <hip/hip_runtime.h>
#include <hip/hip_fp16.h>

// ---- problem constants ----
#define NROWS   32768
#define MT      64          // rows per block
#define NTH     1024        // threads per block (16 waves; wave owns 32 cols)
#define HS      520         // LDS hidden stride in fp16 (512 + 8 pad)
#define OS      148         // LDS out-params stride in float (138 + pad; 16B-aligned rows)
#define BND     3.0f

typedef _Float16 half_t;
typedef __attribute__((ext_vector_type(8))) _Float16 f16x8;
typedef __attribute__((ext_vector_type(4))) _Float16 f16x4;
typedef __attribute__((ext_vector_type(4))) float    f32x4;

// ws layout (fp16 elements), FRAGMENT-ORDERED (unchanged from round 10):
//   fragment (ntile, kstep) = 64 lanes x 8 halfs = 512 halfs = 1KB contiguous,
//   element (n,k): n = nt*16 + (lane&15), k = ks*32 + (lane>>4)*8 + e
//  W0F [8][32 frag][512]      off 0         (NT=32, KS=1;  k>=22 zero)
//  W1F [8][512 frag][512]     off 131072    (NT=32, KS=16)
//  W2F [8][512 frag][512]     off 2228224   (NT=32, KS=16)
//  W3F [8][144 frag][512]     off 4325376   (NT=9,  KS=16; n>=138 zero)

__global__ void pack_frag(const float* __restrict__ src, half_t* __restrict__ dst,
                          int K, int Nn, int NT, int KS) {
  int l = blockIdx.z;
  int frag = blockIdx.x * 4 + (threadIdx.x >> 6);
  int lane = threadIdx.x & 63;
  int NF = NT * KS;
  if (frag >= NF) return;
  int nt = frag / KS, ks = frag - nt * KS;
  int n = nt * 16 + (lane & 15);
  int kb = ks * 32 + (lane >> 4) * 8;
  f16x8 v;
#pragma unroll
  for (int e = 0; e < 8; e++) {
    int k = kb + e;
    v[e] = (k < K && n < Nn) ? (half_t)src[((size_t)l * K + k) * Nn + n] : (half_t)0.f;
  }
  *(f16x8*)(dst + ((size_t)l * NF + frag) * 512 + lane * 8) = v;
}

__device__ __forceinline__ float elu_f(float v) {
  return v > 0.f ? v : (__expf(v) - 1.f);
}

// epilogue: bias + ELU + packed fp16x4 stores (transposed-C layout:
// lane holds 4 consecutive n = w*32 + nt*16 + lk*4 + r at row m = mf*16 + lm)
__device__ __forceinline__ void epi_elu(const f32x4 (&acc)[4][2],
                                        const float* __restrict__ bias,
                                        half_t* dst, int w, int lm, int lk) {
#pragma unroll
  for (int nt = 0; nt < 2; nt++) {
    int n0 = w * 32 + nt * 16 + lk * 4;
    f32x4 bv = *(const f32x4*)(bias + n0);
#pragma unroll
    for (int mf = 0; mf < 4; mf++) {
      f16x4 pv;
#pragma unroll
      for (int r = 0; r < 4; r++) pv[r] = (half_t)elu_f(acc[mf][nt][r] + bv[r]);
      *(f16x4*)(dst + (mf * 16 + lm) * HS + n0) = pv;
    }
  }
}

// layer-0 GEMM: [64 x 32] @ [32 x 512], single k-step; wave w covers cols [w*32, w*32+32)
__device__ __forceinline__ void gemm0(const half_t* A,
                                      const half_t* __restrict__ Wf,   // [32 frag][512]
                                      const float* __restrict__ bias,
                                      half_t* dst, int w, int lane, int lm, int lk) {
  f32x4 acc[4][2];
#pragma unroll
  for (int i = 0; i < 4; i++)
#pragma unroll
    for (int j = 0; j < 2; j++) acc[i][j] = (f32x4){0.f, 0.f, 0.f, 0.f};
  f16x8 b[2];
#pragma unroll
  for (int nt = 0; nt < 2; nt++)
    b[nt] = *(const f16x8*)(Wf + ((size_t)(w * 2 + nt)) * 512 + lane * 8);
  int ko = lk * 8;
  f16x8 a[4];
#pragma unroll
  for (int mf = 0; mf < 4; mf++) a[mf] = *(const f16x8*)(A + (mf * 16 + lm) * 40 + ko);
#pragma unroll
  for (int nt = 0; nt < 2; nt++)
#pragma unroll
    for (int mf = 0; mf < 4; mf++)
      acc[mf][nt] = __builtin_amdgcn_mfma_f32_16x16x32_f16(b[nt], a[mf], acc[mf][nt], 0, 0, 0);
  epi_elu(acc, bias, dst, w, lm, lk);
}

// 512x512 GEMM, ksteps=16, depth-4 register ring for B, depth-2 for A.
// Wave w covers cols [w*32, w*32+32) via nt = 2w, 2w+1.
__device__ __forceinline__ void gemm512(
    const half_t* A, const half_t* __restrict__ Wf,
    const float* __restrict__ bias, half_t* dst,
    int w, int lane, int lm, int lk) {
  f32x4 acc[4][2];
#pragma unroll
  for (int i = 0; i < 4; i++)
#pragma unroll
    for (int j = 0; j < 2; j++) acc[i][j] = (f32x4){0.f, 0.f, 0.f, 0.f};

  f16x8 a[2][4], b[4][2];
#pragma unroll
  for (int s = 0; s < 4; s++)
#pragma unroll
    for (int nt = 0; nt < 2; nt++)
      b[s][nt] = *(const f16x8*)(Wf + ((size_t)((w * 2 + nt) * 16 + s)) * 512 + lane * 8);
#pragma unroll
  for (int s = 0; s < 2; s++) {
    int ko = s * 32 + lk * 8;
#pragma unroll
    for (int mf = 0; mf < 4; mf++)
      a[s][mf] = *(const f16x8*)(A + (mf * 16 + lm) * HS + ko);
  }
#pragma unroll
  for (int ks = 0; ks < 16; ks++) {
    const int sl = ks & 3, asx = ks & 1;
#pragma unroll
    for (int nt = 0; nt < 2; nt++)
#pragma unroll
      for (int mf = 0; mf < 4; mf++)
        acc[mf][nt] = __builtin_amdgcn_mfma_f32_16x16x32_f16(b[sl][nt], a[asx][mf], acc[mf][nt], 0, 0, 0);
    if (ks + 4 < 16) {
#pragma unroll
      for (int nt = 0; nt < 2; nt++)
        b[sl][nt] = *(const f16x8*)(Wf + ((size_t)((w * 2 + nt) * 16 + ks + 4)) * 512 + lane * 8);
    }
    if (ks + 2 < 16) {
      int ko = (ks + 2) * 32 + lk * 8;
#pragma unroll
      for (int mf = 0; mf < 4; mf++)
        a[asx][mf] = *(const f16x8*)(A + (mf * 16 + lm) * HS + ko);
    }
  }
  epi_elu(acc, bias, dst, w, lm, lk);
}

// last GEMM: [64 x 512] @ [512 x 144] -> fp32 outb. 9 n-tiles; wave w<9 takes tile w.
__device__ __forceinline__ void gemm_out(
    const half_t* A, const half_t* __restrict__ Wf,  // [9*16 frags][512]
    const float* __restrict__ bias,                  // [138]
    float* outb, int w, int lane, int lm, int lk) {
  if (w >= 9) return;
  f32x4 acc[4];
#pragma unroll
  for (int i = 0; i < 4; i++) acc[i] = (f32x4){0.f, 0.f, 0.f, 0.f};

  f16x8 a[2][4], b[4];
#pragma unroll
  for (int s = 0; s < 4; s++)
    b[s] = *(const f16x8*)(Wf + ((size_t)(w * 16 + s)) * 512 + lane * 8);
#pragma unroll
  for (int s = 0; s < 2; s++) {
    int ko = s * 32 + lk * 8;
#pragma unroll
    for (int mf = 0; mf < 4; mf++)
      a[s][mf] = *(const f16x8*)(A + (mf * 16 + lm) * HS + ko);
  }
#pragma unroll
  for (int ks = 0; ks < 16; ks++) {
    const int sl = ks & 3, asx = ks & 1;
#pragma unroll
    for (int mf = 0; mf < 4; mf++)
      acc[mf] = __builtin_amdgcn_mfma_f32_16x16x32_f16(b[sl], a[asx][mf], acc[mf], 0, 0, 0);
    if (ks + 4 < 16)
      b[sl] = *(const f16x8*)(Wf + ((size_t)(w * 16 + ks + 4)) * 512 + lane * 8);
    if (ks + 2 < 16) {
      int ko = (ks + 2) * 32 + lk * 8;
#pragma unroll
      for (int mf = 0; mf < 4; mf++)
        a[asx][mf] = *(const f16x8*)(A + (mf * 16 + lm) * HS + ko);
    }
  }
  // epilogue: aligned 16B stores; cols 138..143 get zeros (never read)
  int n0 = w * 16 + lk * 4;
  f32x4 bv;
#pragma unroll
  for (int r = 0; r < 4; r++) bv[r] = (n0 + r < 138) ? bias[n0 + r] : 0.f;
#pragma unroll
  for (int mf = 0; mf < 4; mf++) {
    f32x4 ov = acc[mf] + bv;
    *(f32x4*)(outb + (mf * 16 + lm) * OS + n0) = ov;
  }
}

__global__ __launch_bounds__(NTH, 4) __attribute__((amdgpu_waves_per_eu(4, 4)))
void flow_kernel(const float* __restrict__ z, const float* __restrict__ c,
                 const float* __restrict__ b0, const float* __restrict__ b1,
                 const float* __restrict__ b2, const float* __restrict__ b3,
                 const int* __restrict__ perms,
                 const half_t* __restrict__ W0F, const half_t* __restrict__ W1F,
                 const half_t* __restrict__ W2F, const half_t* __restrict__ W3F,
                 float* __restrict__ out) {
  __shared__ half_t hbufA[MT * HS];                     // 66,560 B
  __shared__ __align__(16) char smemB[MT * HS * 2];     // 66,560 B: h fp16 / out fp32 [MT][OS]
  __shared__ half_t inpb[MT * 40];                      // 5,120 B
  __shared__ half_t cbuf[MT * 16];                      // 2,048 B
  __shared__ float xbuf[MT][12];
  __shared__ float ldpart[MT][6];
  __shared__ float ldtot[MT];
  __shared__ int   permbuf[7][12];

  half_t* hbufB  = (half_t*)smemB;
  float*  outbuf = (float*)smemB;

  int tid = threadIdx.x;
  int w = tid >> 6, lane = tid & 63;
  int lm = lane & 15, lk = lane >> 4;
  int row0 = blockIdx.x * MT;

  if (tid < MT * 12) xbuf[tid / 12][tid % 12] = z[(size_t)row0 * 12 + tid];
  if (tid < MT * 16) cbuf[tid] = (half_t)c[(size_t)row0 * 16 + tid];
  if (tid < 84) permbuf[tid / 12][tid % 12] = perms[tid];
  if (tid < MT) ldtot[tid] = 0.f;
  __syncthreads();

  for (int l = 0; l < 8; l++) {
    // build MLP input [x1(6) | c(16) | 0(10)] as fp16
    for (int it = tid; it < MT * 32; it += NTH) {
      int m = it >> 5, k = it & 31;
      half_t bv;
      if (k < 6)       bv = (half_t)xbuf[m][k];
      else if (k < 22) bv = cbuf[m * 16 + (k - 6)];
      else             bv = (half_t)0.f;
      inpb[m * 40 + k] = bv;
    }
    __syncthreads();
    gemm0(inpb, W0F + (size_t)l * 32 * 512, b0 + l * 512, hbufA, w, lane, lm, lk);
    __syncthreads();
    gemm512(hbufA, W1F + (size_t)l * 512 * 512, b1 + l * 512, hbufB, w, lane, lm, lk);
    __syncthreads();
    gemm512(hbufB, W2F + (size_t)l * 512 * 512, b2 + l * 512, hbufA, w, lane, lm, lk);
    __syncthreads();
    gemm_out(hbufA, W3F + (size_t)l * 144 * 512, b3 + l * 138, outbuf, w, lane, lm, lk);
    __syncthreads();

    // ---- rational-quadratic spline, one thread per (row, dim) ----
    if (tid < MT * 6) {
      int m = tid / 6, j = tid % 6;
      const float* pr = outbuf + m * OS + j * 23;
      float uw[8], uh[8], dd[9];
#pragma unroll
      for (int i = 0; i < 8; i++) uw[i] = pr[i];
#pragma unroll
      for (int i = 0; i < 8; i++) uh[i] = pr[8 + i];
      dd[0] = 1.f; dd[8] = 1.f;   // MIN_D + softplus(DERIV_CONST) == 1 exactly
#pragma unroll
      for (int i = 0; i < 7; i++) {
        float u = pr[16 + i];
        float sp = (u > 15.f) ? u : log1pf(__expf(u));
        dd[i + 1] = 0.001f + sp;
      }
      float mw = uw[0];
#pragma unroll
      for (int i = 1; i < 8; i++) mw = fmaxf(mw, uw[i]);
      float ew[8], sw = 0.f;
#pragma unroll
      for (int i = 0; i < 8; i++) { ew[i] = __expf(uw[i] - mw); sw += ew[i]; }
      float invw = 1.f / sw;
      float cw[9]; cw[0] = -BND;
      float a = 0.f;
#pragma unroll
      for (int i = 0; i < 8; i++) { a += 0.001f + 0.992f * ew[i] * invw; cw[i + 1] = 2.f * BND * a - BND; }
      cw[8] = BND;
      float mh = uh[0];
#pragma unroll
      for (int i = 1; i < 8; i++) mh = fmaxf(mh, uh[i]);
      float eh[8], sh = 0.f;
#pragma unroll
      for (int i = 0; i < 8; i++) { eh[i] = __expf(uh[i] - mh); sh += eh[i]; }
      float invh = 1.f / sh;
      float ch[9]; ch[0] = -BND;
      float ah = 0.f;
#pragma unroll
      for (int i = 0; i < 8; i++) { ah += 0.001f + 0.992f * eh[i] * invh; ch[i + 1] = 2.f * BND * ah - BND; }
      ch[8] = BND;

      float x2 = xbuf[m][6 + j];
      float xc = fminf(fmaxf(x2, -BND), BND);
      int cnt = 0;
#pragma unroll
      for (int i = 0; i < 9; i++) {
        float edge = (i == 8) ? (cw[8] + 1e-6f) : cw[i];
        cnt += (xc >= edge) ? 1 : 0;
      }
      int idx = cnt - 1; idx = idx < 0 ? 0 : (idx > 7 ? 7 : idx);
      float icw = cw[0], iw = cw[1] - cw[0], ich = ch[0], ih = ch[1] - ch[0], d0 = dd[0], d1 = dd[1];
#pragma unroll
      for (int i = 0; i < 8; i++) {
        if (idx == i) {
          icw = cw[i]; iw = cw[i + 1] - cw[i];
          ich = ch[i]; ih = ch[i + 1] - ch[i];
          d0 = dd[i]; d1 = dd[i + 1];
        }
      }
      float delta = ih / iw;
      float th  = (xc - icw) / iw;
      float t1m = th * (1.f - th);
      float num = ih * (delta * th * th + d0 * t1m);
      float den = delta + (d0 + d1 - 2.f * delta) * t1m;
      float outv = ich + num / den;
      float dnum = delta * delta * (d1 * th * th + 2.f * delta * t1m + d0 * (1.f - th) * (1.f - th));
      float lad = logf(dnum) - 2.f * logf(den);
      bool inside = (x2 >= -BND) && (x2 <= BND);
      xbuf[m][6 + j] = inside ? outv : x2;
      ldpart[m][j]   = inside ? lad : 0.f;
    }
    __syncthreads();
    if (tid < MT) {
      float s = ldtot[tid];
#pragma unroll
      for (int j = 0; j < 6; j++) s += ldpart[tid][j];
      ldtot[tid] = s;
    }
    if (l < 7) {
      // permute xbuf rows: 768 elements, one per thread (tid < 768)
      float v0 = 0.f;
      if (tid < MT * 12) v0 = xbuf[tid / 12][permbuf[l][tid % 12]];
      __syncthreads();
      if (tid < MT * 12) xbuf[tid / 12][tid % 12] = v0;
    }
    __syncthreads();
  }

  if (tid < MT * 12) out[(size_t)row0 * 12 + tid] = xbuf[tid / 12][tid % 12];
  if (tid < MT) out[(size_t)NROWS * 12 + row0 + tid] = ldtot[tid];
}

extern "C" void kernel_launch(void* const* d_in, const int* in_sizes, int n_in,
                              void* d_out, int out_size, void* d_ws, size_t ws_size,
                              hipStream_t stream) {
  const float* z  = (const float*)d_in[0];
  const float* c  = (const float*)d_in[1];
  const float* W0 = (const float*)d_in[2];
  const float* b0 = (const float*)d_in[3];
  const float* W1 = (const float*)d_in[4];
  const float* b1 = (const float*)d_in[5];
  const float* W2 = (const float*)d_in[6];
  const float* b2 = (const float*)d_in[7];
  const float* W3 = (const float*)d_in[8];
  const float* b3 = (const float*)d_in[9];
  const int* perms = (const int*)d_in[10];

  unsigned short* wsu = (unsigned short*)d_ws;
  half_t* W0F = (half_t*)(wsu + 0);         // [8][32 frag][512]
  half_t* W1F = (half_t*)(wsu + 131072);    // [8][512 frag][512]
  half_t* W2F = (half_t*)(wsu + 2228224);   // [8][512 frag][512]
  half_t* W3F = (half_t*)(wsu + 4325376);   // [8][144 frag][512]

  // pack: 256 threads = 4 fragments per block
  pack_frag<<<dim3(8,   1, 8), dim3(256), 0, stream>>>(W0, W0F, 22,  512, 32, 1);
  pack_frag<<<dim3(128, 1, 8), dim3(256), 0, stream>>>(W1, W1F, 512, 512, 32, 16);
  pack_frag<<<dim3(128, 1, 8), dim3(256), 0, stream>>>(W2, W2F, 512, 512, 32, 16);
  pack_frag<<<dim3(36,  1, 8), dim3(256), 0, stream>>>(W3, W3F, 512, 138, 9,  16);

  flow_kernel<<<dim3(NROWS / MT), dim3(NTH), 0, stream>>>(
      z, c, b0, b1, b2, b3, perms, W0F, W1F, W2F, W3F, (float*)d_out);
}

// Round 13
// 551.691 us; speedup vs baseline: 1.1352x; 1.1352x over previous
//
#include <hip/hip_runtime.h>
#include <hip/hip_fp16.h>

// ---- problem constants ----
#define NROWS   32768
#define MT      64          // rows per block
#define NTH     512         // threads per block (8 waves; wave owns 64 cols, in 2 passes of 32)
#define HS      520         // LDS hidden stride in fp16 (512 + 8 pad)
#define OS      148         // LDS out-params stride in float (138 + pad; 16B-aligned rows)
#define BND     3.0f

typedef _Float16 half_t;
typedef __attribute__((ext_vector_type(8))) _Float16 f16x8;
typedef __attribute__((ext_vector_type(4))) _Float16 f16x4;
typedef __attribute__((ext_vector_type(4))) float    f32x4;

// ws layout (fp16 elements), FRAGMENT-ORDERED:
//   fragment (ntile, kstep) = 64 lanes x 8 halfs = 512 halfs = 1KB contiguous,
//   element (n,k): n = nt*16 + (lane&15), k = ks*32 + (lane>>4)*8 + e
//  W0F [8][32 frag][512]      off 0         (NT=32, KS=1;  k>=22 zero)
//  W1F [8][512 frag][512]     off 131072    (NT=32, KS=16)
//  W2F [8][512 frag][512]     off 2228224   (NT=32, KS=16)
//  W3F [8][144 frag][512]     off 4325376   (NT=9,  KS=16; n>=138 zero)

__global__ void pack_frag(const float* __restrict__ src, half_t* __restrict__ dst,
                          int K, int Nn, int NT, int KS) {
  int l = blockIdx.z;
  int frag = blockIdx.x * 4 + (threadIdx.x >> 6);
  int lane = threadIdx.x & 63;
  int NF = NT * KS;
  if (frag >= NF) return;
  int nt = frag / KS, ks = frag - nt * KS;
  int n = nt * 16 + (lane & 15);
  int kb = ks * 32 + (lane >> 4) * 8;
  f16x8 v;
#pragma unroll
  for (int e = 0; e < 8; e++) {
    int k = kb + e;
    v[e] = (k < K && n < Nn) ? (half_t)src[((size_t)l * K + k) * Nn + n] : (half_t)0.f;
  }
  *(f16x8*)(dst + ((size_t)l * NF + frag) * 512 + lane * 8) = v;
}

__device__ __forceinline__ float elu_f(float v) {
  return v > 0.f ? v : (__expf(v) - 1.f);
}

// GEMM: [64 x K] (LDS fp16, stride as) @ [K x 512] (global, fragment-ordered)
// -> elu(. + bias) -> dst LDS fp16 [64][HS]. Wave w covers cols [w*64, w*64+64)
// in TWO sequential 32-col passes so the depth-4 B-ring + depth-2 A-ring fit
// inside the 128-VGPR budget. Pass 0's k-loop tail prefills pass 1's rings
// (no barrier needed: A read-only, write cols disjoint).
// TRANSPOSED MFMA: mfma(W,A,acc) -> lane holds 4 consecutive n at row m.
__device__ __forceinline__ void gemm_elu(
    const half_t* A, int as, int ksteps,
    const half_t* __restrict__ Wf, int KSW,
    const float* __restrict__ bias,
    half_t* dst,
    int w, int lane, int lm, int lk) {
  f16x8 a[2][4], b[4][2];
#pragma unroll
  for (int half = 0; half < 2; half++) {
    const int ntb = w * 4 + half * 2;
    f32x4 acc[4][2];
#pragma unroll
    for (int i = 0; i < 4; i++)
#pragma unroll
      for (int j = 0; j < 2; j++) acc[i][j] = (f32x4){0.f, 0.f, 0.f, 0.f};

    const bool prefilled = (ksteps == 16) && (half == 1);
    if (!prefilled) {
#pragma unroll
      for (int s = 0; s < 4; s++)
        if (s < ksteps) {
#pragma unroll
          for (int nt = 0; nt < 2; nt++)
            b[s][nt] = *(const f16x8*)(Wf + ((size_t)((ntb + nt) * KSW + s)) * 512 + lane * 8);
        }
#pragma unroll
      for (int s = 0; s < 2; s++)
        if (s < ksteps) {
          int ko = s * 32 + lk * 8;
#pragma unroll
          for (int mf = 0; mf < 4; mf++)
            a[s][mf] = *(const f16x8*)(A + (mf * 16 + lm) * as + ko);
        }
    }
#pragma unroll
    for (int ks = 0; ks < ksteps; ks++) {
      const int sl = ks & 3, asx = ks & 1;
#pragma unroll
      for (int nt = 0; nt < 2; nt++)
#pragma unroll
        for (int mf = 0; mf < 4; mf++)
          acc[mf][nt] = __builtin_amdgcn_mfma_f32_16x16x32_f16(b[sl][nt], a[asx][mf], acc[mf][nt], 0, 0, 0);
      // B refill: own steps, then (pass 0 only) pass-1 steps 0..3
      if (ks + 4 < ksteps) {
#pragma unroll
        for (int nt = 0; nt < 2; nt++)
          b[sl][nt] = *(const f16x8*)(Wf + ((size_t)((ntb + nt) * KSW + ks + 4)) * 512 + lane * 8);
      } else if (ksteps == 16 && half == 0) {
#pragma unroll
        for (int nt = 0; nt < 2; nt++)
          b[sl][nt] = *(const f16x8*)(Wf + ((size_t)((ntb + 2 + nt) * KSW + (ks - 12))) * 512 + lane * 8);
      }
      // A refill: own chunks, then (pass 0 only) chunks 0..1 for pass 1
      if (ks + 2 < ksteps) {
        int ko = (ks + 2) * 32 + lk * 8;
#pragma unroll
        for (int mf = 0; mf < 4; mf++)
          a[asx][mf] = *(const f16x8*)(A + (mf * 16 + lm) * HS + ko);
      } else if (ksteps == 16 && half == 0) {
        int ko = (ks - 14) * 32 + lk * 8;
#pragma unroll
        for (int mf = 0; mf < 4; mf++)
          a[asx][mf] = *(const f16x8*)(A + (mf * 16 + lm) * HS + ko);
      }
    }
    // epilogue: lane writes 4 consecutive n (packed fp16x4, 8B) per (mf, nt)
#pragma unroll
    for (int nt = 0; nt < 2; nt++) {
      int n0 = w * 64 + half * 32 + nt * 16 + lk * 4;
      f32x4 bv = *(const f32x4*)(bias + n0);
#pragma unroll
      for (int mf = 0; mf < 4; mf++) {
        f16x4 pv;
#pragma unroll
        for (int r = 0; r < 4; r++) pv[r] = (half_t)elu_f(acc[mf][nt][r] + bv[r]);
        *(f16x4*)(dst + (mf * 16 + lm) * HS + n0) = pv;
      }
    }
  }
}

// last GEMM: [64 x 512] @ [512 x 144] -> fp32 outb (round-10 champion version).
// 9 n-tiles over 8 waves: wave w -> tile w; wave 0 also tile 8.
__device__ __forceinline__ void gemm_out(
    const half_t* A,
    const half_t* __restrict__ Wf,        // [9*16 frags][512]
    const float* __restrict__ bias,       // [138]
    float* outb,
    int w, int lane, int lm, int lk) {
  f32x4 acc[4][2];
#pragma unroll
  for (int i = 0; i < 4; i++)
#pragma unroll
    for (int j = 0; j < 2; j++) acc[i][j] = (f32x4){0.f, 0.f, 0.f, 0.f};
  const bool has2 = (w == 0);

  f16x8 a[2][4], b[4][2];
#pragma unroll
  for (int s = 0; s < 4; s++) {
    b[s][0] = *(const f16x8*)(Wf + ((size_t)(w * 16 + s)) * 512 + lane * 8);
    if (has2) b[s][1] = *(const f16x8*)(Wf + ((size_t)(8 * 16 + s)) * 512 + lane * 8);
  }
#pragma unroll
  for (int s = 0; s < 2; s++) {
    int ko = s * 32 + lk * 8;
#pragma unroll
    for (int mf = 0; mf < 4; mf++)
      a[s][mf] = *(const f16x8*)(A + (mf * 16 + lm) * HS + ko);
  }
#pragma unroll
  for (int ks = 0; ks < 16; ks++) {
    const int sl = ks & 3, asx = ks & 1;
#pragma unroll
    for (int mf = 0; mf < 4; mf++)
      acc[mf][0] = __builtin_amdgcn_mfma_f32_16x16x32_f16(b[sl][0], a[asx][mf], acc[mf][0], 0, 0, 0);
    if (has2)
#pragma unroll
      for (int mf = 0; mf < 4; mf++)
        acc[mf][1] = __builtin_amdgcn_mfma_f32_16x16x32_f16(b[sl][1], a[asx][mf], acc[mf][1], 0, 0, 0);
    if (ks + 4 < 16) {
      b[sl][0] = *(const f16x8*)(Wf + ((size_t)(w * 16 + ks + 4)) * 512 + lane * 8);
      if (has2) b[sl][1] = *(const f16x8*)(Wf + ((size_t)(128 + ks + 4)) * 512 + lane * 8);
    }
    if (ks + 2 < 16) {
      int ko = (ks + 2) * 32 + lk * 8;
#pragma unroll
      for (int mf = 0; mf < 4; mf++)
        a[asx][mf] = *(const f16x8*)(A + (mf * 16 + lm) * HS + ko);
    }
  }
  // epilogue: aligned 16B stores; cols 138..143 get zeros (never read)
  {
    int n0 = w * 16 + lk * 4;
    f32x4 bv = *(const f32x4*)(bias + n0);
#pragma unroll
    for (int mf = 0; mf < 4; mf++) {
      f32x4 ov = acc[mf][0] + bv;
      *(f32x4*)(outb + (mf * 16 + lm) * OS + n0) = ov;
    }
  }
  if (has2) {
    int n0 = 128 + lk * 4;
    f32x4 bv;
#pragma unroll
    for (int r = 0; r < 4; r++) bv[r] = (n0 + r < 138) ? bias[n0 + r] : 0.f;
#pragma unroll
    for (int mf = 0; mf < 4; mf++) {
      f32x4 ov = acc[mf][1] + bv;
      *(f32x4*)(outb + (mf * 16 + lm) * OS + n0) = ov;
    }
  }
}

__global__ __launch_bounds__(NTH, 2) __attribute__((amdgpu_waves_per_eu(2, 2)))
void flow_kernel(const float* __restrict__ z, const float* __restrict__ c,
                 const float* __restrict__ b0, const float* __restrict__ b1,
                 const float* __restrict__ b2, const float* __restrict__ b3,
                 const int* __restrict__ perms,
                 const half_t* __restrict__ W0F, const half_t* __restrict__ W1F,
                 const half_t* __restrict__ W2F, const half_t* __restrict__ W3F,
                 float* __restrict__ out) {
  __shared__ half_t hbufA[MT * HS];                     // 66,560 B
  __shared__ __align__(16) char smemB[MT * HS * 2];     // 66,560 B: h fp16 / out fp32 [MT][OS]
  __shared__ half_t inpb[MT * 40];                      // 5,120 B
  __shared__ half_t cbuf[MT * 16];                      // 2,048 B
  __shared__ float xbuf[MT][12];
  __shared__ float ldpart[MT][6];
  __shared__ float ldtot[MT];
  __shared__ int   permbuf[7][12];

  half_t* hbufB  = (half_t*)smemB;
  float*  outbuf = (float*)smemB;

  int tid = threadIdx.x;
  int w = tid >> 6, lane = tid & 63;
  int lm = lane & 15, lk = lane >> 4;
  int row0 = blockIdx.x * MT;

  for (int it = tid; it < MT * 12; it += NTH) xbuf[it / 12][it % 12] = z[(size_t)row0 * 12 + it];
  for (int it = tid; it < MT * 16; it += NTH) cbuf[it] = (half_t)c[(size_t)row0 * 16 + it];
  for (int it = tid; it < 84; it += NTH) permbuf[it / 12][it % 12] = perms[it];
  if (tid < MT) ldtot[tid] = 0.f;
  __syncthreads();

  for (int l = 0; l < 8; l++) {
    // build MLP input [x1(6) | c(16) | 0(10)] as fp16
    for (int it = tid; it < MT * 32; it += NTH) {
      int m = it >> 5, k = it & 31;
      half_t bv;
      if (k < 6)       bv = (half_t)xbuf[m][k];
      else if (k < 22) bv = cbuf[m * 16 + (k - 6)];
      else             bv = (half_t)0.f;
      inpb[m * 40 + k] = bv;
    }
    __syncthreads();
    gemm_elu(inpb, 40, 1,  W0F + (size_t)l * 32 * 512,      1,  b0 + l * 512, hbufA, w, lane, lm, lk);
    __syncthreads();
    gemm_elu(hbufA, HS, 16, W1F + (size_t)l * 512 * 512,   16,  b1 + l * 512, hbufB, w, lane, lm, lk);
    __syncthreads();
    gemm_elu(hbufB, HS, 16, W2F + (size_t)l * 512 * 512,   16,  b2 + l * 512, hbufA, w, lane, lm, lk);
    __syncthreads();
    gemm_out(hbufA, W3F + (size_t)l * 144 * 512, b3 + l * 138, outbuf, w, lane, lm, lk);
    __syncthreads();

    // ---- rational-quadratic spline, one thread per (row, dim) ----
    if (tid < MT * 6) {
      int m = tid / 6, j = tid % 6;
      const float* pr = outbuf + m * OS + j * 23;
      float uw[8], uh[8], dd[9];
#pragma unroll
      for (int i = 0; i < 8; i++) uw[i] = pr[i];
#pragma unroll
      for (int i = 0; i < 8; i++) uh[i] = pr[8 + i];
      dd[0] = 1.f; dd[8] = 1.f;   // MIN_D + softplus(DERIV_CONST) == 1 exactly
#pragma unroll
      for (int i = 0; i < 7; i++) {
        float u = pr[16 + i];
        float sp = (u > 15.f) ? u : log1pf(__expf(u));
        dd[i + 1] = 0.001f + sp;
      }
      float mw = uw[0];
#pragma unroll
      for (int i = 1; i < 8; i++) mw = fmaxf(mw, uw[i]);
      float ew[8], sw = 0.f;
#pragma unroll
      for (int i = 0; i < 8; i++) { ew[i] = __expf(uw[i] - mw); sw += ew[i]; }
      float invw = 1.f / sw;
      float cw[9]; cw[0] = -BND;
      float a = 0.f;
#pragma unroll
      for (int i = 0; i < 8; i++) { a += 0.001f + 0.992f * ew[i] * invw; cw[i + 1] = 2.f * BND * a - BND; }
      cw[8] = BND;
      float mh = uh[0];
#pragma unroll
      for (int i = 1; i < 8; i++) mh = fmaxf(mh, uh[i]);
      float eh[8], sh = 0.f;
#pragma unroll
      for (int i = 0; i < 8; i++) { eh[i] = __expf(uh[i] - mh); sh += eh[i]; }
      float invh = 1.f / sh;
      float ch[9]; ch[0] = -BND;
      float ah = 0.f;
#pragma unroll
      for (int i = 0; i < 8; i++) { ah += 0.001f + 0.992f * eh[i] * invh; ch[i + 1] = 2.f * BND * ah - BND; }
      ch[8] = BND;

      float x2 = xbuf[m][6 + j];
      float xc = fminf(fmaxf(x2, -BND), BND);
      int cnt = 0;
#pragma unroll
      for (int i = 0; i < 9; i++) {
        float edge = (i == 8) ? (cw[8] + 1e-6f) : cw[i];
        cnt += (xc >= edge) ? 1 : 0;
      }
      int idx = cnt - 1; idx = idx < 0 ? 0 : (idx > 7 ? 7 : idx);
      float icw = cw[0], iw = cw[1] - cw[0], ich = ch[0], ih = ch[1] - ch[0], d0 = dd[0], d1 = dd[1];
#pragma unroll
      for (int i = 0; i < 8; i++) {
        if (idx == i) {
          icw = cw[i]; iw = cw[i + 1] - cw[i];
          ich = ch[i]; ih = ch[i + 1] - ch[i];
          d0 = dd[i]; d1 = dd[i + 1];
        }
      }
      float delta = ih / iw;
      float th  = (xc - icw) / iw;
      float t1m = th * (1.f - th);
      float num = ih * (delta * th * th + d0 * t1m);
      float den = delta + (d0 + d1 - 2.f * delta) * t1m;
      float outv = ich + num / den;
      float dnum = delta * delta * (d1 * th * th + 2.f * delta * t1m + d0 * (1.f - th) * (1.f - th));
      float lad = logf(dnum) - 2.f * logf(den);
      bool inside = (x2 >= -BND) && (x2 <= BND);
      xbuf[m][6 + j] = inside ? outv : x2;
      ldpart[m][j]   = inside ? lad : 0.f;
    }
    __syncthreads();
    if (tid < MT) {
      float s = ldtot[tid];
#pragma unroll
      for (int j = 0; j < 6; j++) s += ldpart[tid][j];
      ldtot[tid] = s;
    }
    if (l < 7) {
      // permute xbuf rows: 768 elements over 512 threads
      float v0 = xbuf[tid / 12][permbuf[l][tid % 12]];
      float v1 = 0.f;
      int it1 = tid + NTH;
      if (it1 < MT * 12) v1 = xbuf[it1 / 12][permbuf[l][it1 % 12]];
      __syncthreads();
      xbuf[tid / 12][tid % 12] = v0;
      if (it1 < MT * 12) xbuf[it1 / 12][it1 % 12] = v1;
    }
    __syncthreads();
  }

  for (int it = tid; it < MT * 12; it += NTH) out[(size_t)row0 * 12 + it] = xbuf[it / 12][it % 12];
  if (tid < MT) out[(size_t)NROWS * 12 + row0 + tid] = ldtot[tid];
}

extern "C" void kernel_launch(void* const* d_in, const int* in_sizes, int n_in,
                              void* d_out, int out_size, void* d_ws, size_t ws_size,
                              hipStream_t stream) {
  const float* z  = (const float*)d_in[0];
  const float* c  = (const float*)d_in[1];
  const float* W0 = (const float*)d_in[2];
  const float* b0 = (const float*)d_in[3];
  const float* W1 = (const float*)d_in[4];
  const float* b1 = (const float*)d_in[5];
  const float* W2 = (const float*)d_in[6];
  const float* b2 = (const float*)d_in[7];
  const float* W3 = (const float*)d_in[8];
  const float* b3 = (const float*)d_in[9];
  const int* perms = (const int*)d_in[10];

  unsigned short* wsu = (unsigned short*)d_ws;
  half_t* W0F = (half_t*)(wsu + 0);         // [8][32 frag][512]
  half_t* W1F = (half_t*)(wsu + 131072);    // [8][512 frag][512]
  half_t* W2F = (half_t*)(wsu + 2228224);   // [8][512 frag][512]
  half_t* W3F = (half_t*)(wsu + 4325376);   // [8][144 frag][512]

  // pack: 256 threads = 4 fragments per block
  pack_frag<<<dim3(8,   1, 8), dim3(256), 0, stream>>>(W0, W0F, 22,  512, 32, 1);
  pack_frag<<<dim3(128, 1, 8), dim3(256), 0, stream>>>(W1, W1F, 512, 512, 32, 16);
  pack_frag<<<dim3(128, 1, 8), dim3(256), 0, stream>>>(W2, W2F, 512, 512, 32, 16);
  pack_frag<<<dim3(36,  1, 8), dim3(256), 0, stream>>>(W3, W3F, 512, 138, 9,  16);

  flow_kernel<<<dim3(NROWS / MT), dim3(NTH), 0, stream>>>(
      z, c, b0, b1, b2, b3, perms, W0F, W1F, W2F, W3F, (float*)d_out);
}

// Round 14
// 502.390 us; speedup vs baseline: 1.2466x; 1.0981x over previous
//
#include <hip/hip_runtime.h>
#include <hip/hip_fp16.h>

// ---- problem constants ----
#define NROWS   32768
#define MT      64          // rows per block
#define NTH     512         // threads per block (8 waves; wave owns 64 cols, 2 passes of 32)
#define OS      148         // LDS out-params stride in float (138 + pad; 16B-aligned rows)
#define BND     3.0f

typedef _Float16 half_t;
typedef __attribute__((ext_vector_type(8))) _Float16 f16x8;
typedef __attribute__((ext_vector_type(4))) _Float16 f16x4;
typedef __attribute__((ext_vector_type(4))) float    f32x4;

// Weights (global ws), FRAGMENT-ORDERED (unchanged):
//   fragment (ntile, kstep) = 64 lanes x 8 halfs = 1KB; element (n,k):
//   n = nt*16 + (lane&15), k = ks*32 + (lane>>4)*8 + e
//  W0F [8][32 frag][512], W1F/W2F [8][512 frag][512], W3F [8][144 frag][512]
//
// Hidden activations (LDS) now ALSO fragment-ordered (A-operand order):
//   buffer = [4 mf][KSA ks][64 lanes][8 halfs]; element (m, k):
//   m = mf*16 + (lane&15), k = ks*32 + (lane>>4)*8 + e
//   read:  frag*1024B + lane*16B  -> sequential, conflict-free ds_read_b128

__global__ void pack_frag(const float* __restrict__ src, half_t* __restrict__ dst,
                          int K, int Nn, int NT, int KS) {
  int l = blockIdx.z;
  int frag = blockIdx.x * 4 + (threadIdx.x >> 6);
  int lane = threadIdx.x & 63;
  int NF = NT * KS;
  if (frag >= NF) return;
  int nt = frag / KS, ks = frag - nt * KS;
  int n = nt * 16 + (lane & 15);
  int kb = ks * 32 + (lane >> 4) * 8;
  f16x8 v;
#pragma unroll
  for (int e = 0; e < 8; e++) {
    int k = kb + e;
    v[e] = (k < K && n < Nn) ? (half_t)src[((size_t)l * K + k) * Nn + n] : (half_t)0.f;
  }
  *(f16x8*)(dst + ((size_t)l * NF + frag) * 512 + lane * 8) = v;
}

__device__ __forceinline__ float elu_f(float v) {
  return v > 0.f ? v : (__expf(v) - 1.f);
}

// GEMM: [64 x K] (LDS fp16, fragment-ordered, KSA ksteps) @ [K x 512] (global)
// -> elu(. + bias) -> dst LDS fp16 (fragment-ordered, 16 ksteps).
// Wave w covers cols [w*64, w*64+64) in TWO 32-col passes (128-VGPR budget);
// pass 0's k-loop tail prefills pass 1's rings.
// TRANSPOSED MFMA: mfma(W,A,acc) -> lane holds 4 consecutive n at row m.
__device__ __forceinline__ void gemm_elu(
    const half_t* A, int KSA, int ksteps,
    const half_t* __restrict__ Wf, int KSW,
    const float* __restrict__ bias,
    half_t* dst,
    int w, int lane, int lm, int lk) {
  f16x8 a[2][4], b[4][2];
#pragma unroll
  for (int half = 0; half < 2; half++) {
    const int ntb = w * 4 + half * 2;
    f32x4 acc[4][2];
#pragma unroll
    for (int i = 0; i < 4; i++)
#pragma unroll
      for (int j = 0; j < 2; j++) acc[i][j] = (f32x4){0.f, 0.f, 0.f, 0.f};

    const bool prefilled = (ksteps == 16) && (half == 1);
    if (!prefilled) {
#pragma unroll
      for (int s = 0; s < 4; s++)
        if (s < ksteps) {
#pragma unroll
          for (int nt = 0; nt < 2; nt++)
            b[s][nt] = *(const f16x8*)(Wf + ((size_t)((ntb + nt) * KSW + s)) * 512 + lane * 8);
        }
#pragma unroll
      for (int s = 0; s < 2; s++)
        if (s < ksteps) {
#pragma unroll
          for (int mf = 0; mf < 4; mf++)
            a[s][mf] = *(const f16x8*)(A + ((size_t)(mf * KSA + s)) * 512 + lane * 8);
        }
    }
#pragma unroll
    for (int ks = 0; ks < ksteps; ks++) {
      const int sl = ks & 3, asx = ks & 1;
#pragma unroll
      for (int nt = 0; nt < 2; nt++)
#pragma unroll
        for (int mf = 0; mf < 4; mf++)
          acc[mf][nt] = __builtin_amdgcn_mfma_f32_16x16x32_f16(b[sl][nt], a[asx][mf], acc[mf][nt], 0, 0, 0);
      // B refill: own steps, then (pass 0 only) pass-1 steps 0..3
      if (ks + 4 < ksteps) {
#pragma unroll
        for (int nt = 0; nt < 2; nt++)
          b[sl][nt] = *(const f16x8*)(Wf + ((size_t)((ntb + nt) * KSW + ks + 4)) * 512 + lane * 8);
      } else if (ksteps == 16 && half == 0) {
#pragma unroll
        for (int nt = 0; nt < 2; nt++)
          b[sl][nt] = *(const f16x8*)(Wf + ((size_t)((ntb + 2 + nt) * KSW + (ks - 12))) * 512 + lane * 8);
      }
      // A refill: own chunks, then (pass 0 only) chunks 0..1 for pass 1
      if (ks + 2 < ksteps) {
#pragma unroll
        for (int mf = 0; mf < 4; mf++)
          a[asx][mf] = *(const f16x8*)(A + ((size_t)(mf * KSA + ks + 2)) * 512 + lane * 8);
      } else if (ksteps == 16 && half == 0) {
#pragma unroll
        for (int mf = 0; mf < 4; mf++)
          a[asx][mf] = *(const f16x8*)(A + ((size_t)(mf * KSA + (ks - 14))) * 512 + lane * 8);
      }
    }
    // epilogue -> dst in A-fragment order: element (m = mf*16+lm, k = n0+r)
    // frag = mf*16 + (w*2+half); lane_dst = (nt*2 + (lk>>1))*16 + lm; elem off (lk&1)*4
    {
      const int ksg = w * 2 + half;
#pragma unroll
      for (int nt = 0; nt < 2; nt++) {
        int n0 = w * 64 + half * 32 + nt * 16 + lk * 4;
        f32x4 bv = *(const f32x4*)(bias + n0);
        int lane_dst = (nt * 2 + (lk >> 1)) * 16 + lm;
#pragma unroll
        for (int mf = 0; mf < 4; mf++) {
          f16x4 pv;
#pragma unroll
          for (int r = 0; r < 4; r++) pv[r] = (half_t)elu_f(acc[mf][nt][r] + bv[r]);
          *(f16x4*)(dst + ((size_t)(mf * 16 + ksg)) * 512 + lane_dst * 8 + (lk & 1) * 4) = pv;
        }
      }
    }
  }
}

// last GEMM: [64 x 512] (fragment-ordered A) @ [512 x 144] -> fp32 outb (row-major).
// 9 n-tiles over 8 waves: wave w -> tile w; wave 0 also tile 8.
__device__ __forceinline__ void gemm_out(
    const half_t* A,
    const half_t* __restrict__ Wf,        // [9*16 frags][512]
    const float* __restrict__ bias,       // [138]
    float* outb,
    int w, int lane, int lm, int lk) {
  f32x4 acc[4][2];
#pragma unroll
  for (int i = 0; i < 4; i++)
#pragma unroll
    for (int j = 0; j < 2; j++) acc[i][j] = (f32x4){0.f, 0.f, 0.f, 0.f};
  const bool has2 = (w == 0);

  f16x8 a[2][4], b[4][2];
#pragma unroll
  for (int s = 0; s < 4; s++) {
    b[s][0] = *(const f16x8*)(Wf + ((size_t)(w * 16 + s)) * 512 + lane * 8);
    if (has2) b[s][1] = *(const f16x8*)(Wf + ((size_t)(8 * 16 + s)) * 512 + lane * 8);
  }
#pragma unroll
  for (int s = 0; s < 2; s++) {
#pragma unroll
    for (int mf = 0; mf < 4; mf++)
      a[s][mf] = *(const f16x8*)(A + ((size_t)(mf * 16 + s)) * 512 + lane * 8);
  }
#pragma unroll
  for (int ks = 0; ks < 16; ks++) {
    const int sl = ks & 3, asx = ks & 1;
#pragma unroll
    for (int mf = 0; mf < 4; mf++)
      acc[mf][0] = __builtin_amdgcn_mfma_f32_16x16x32_f16(b[sl][0], a[asx][mf], acc[mf][0], 0, 0, 0);
    if (has2)
#pragma unroll
      for (int mf = 0; mf < 4; mf++)
        acc[mf][1] = __builtin_amdgcn_mfma_f32_16x16x32_f16(b[sl][1], a[asx][mf], acc[mf][1], 0, 0, 0);
    if (ks + 4 < 16) {
      b[sl][0] = *(const f16x8*)(Wf + ((size_t)(w * 16 + ks + 4)) * 512 + lane * 8);
      if (has2) b[sl][1] = *(const f16x8*)(Wf + ((size_t)(128 + ks + 4)) * 512 + lane * 8);
    }
    if (ks + 2 < 16) {
#pragma unroll
      for (int mf = 0; mf < 4; mf++)
        a[asx][mf] = *(const f16x8*)(A + ((size_t)(mf * 16 + ks + 2)) * 512 + lane * 8);
    }
  }
  // epilogue: aligned 16B stores; cols 138..143 get zeros (never read)
  {
    int n0 = w * 16 + lk * 4;
    f32x4 bv = *(const f32x4*)(bias + n0);
#pragma unroll
    for (int mf = 0; mf < 4; mf++) {
      f32x4 ov = acc[mf][0] + bv;
      *(f32x4*)(outb + (mf * 16 + lm) * OS + n0) = ov;
    }
  }
  if (has2) {
    int n0 = 128 + lk * 4;
    f32x4 bv;
#pragma unroll
    for (int r = 0; r < 4; r++) bv[r] = (n0 + r < 138) ? bias[n0 + r] : 0.f;
#pragma unroll
    for (int mf = 0; mf < 4; mf++) {
      f32x4 ov = acc[mf][1] + bv;
      *(f32x4*)(outb + (mf * 16 + lm) * OS + n0) = ov;
    }
  }
}

__global__ __launch_bounds__(NTH, 2) __attribute__((amdgpu_waves_per_eu(2, 2)))
void flow_kernel(const float* __restrict__ z, const float* __restrict__ c,
                 const float* __restrict__ b0, const float* __restrict__ b1,
                 const float* __restrict__ b2, const float* __restrict__ b3,
                 const int* __restrict__ perms,
                 const half_t* __restrict__ W0F, const half_t* __restrict__ W1F,
                 const half_t* __restrict__ W2F, const half_t* __restrict__ W3F,
                 float* __restrict__ out) {
  __shared__ half_t hbufA[4 * 16 * 512];                // 65,536 B (fragment-ordered)
  __shared__ __align__(16) char smemB[4 * 16 * 512 * 2];// 65,536 B: h frag-fp16 / out fp32 [MT][OS]
  __shared__ half_t inpb[4 * 512];                      // 4,096 B (fragment-ordered, KSA=1)
  __shared__ half_t cbuf[MT * 16];                      // 2,048 B
  __shared__ float xbuf[MT][12];
  __shared__ float ldpart[MT][6];
  __shared__ float ldtot[MT];
  __shared__ int   permbuf[7][12];

  half_t* hbufB  = (half_t*)smemB;
  float*  outbuf = (float*)smemB;

  int tid = threadIdx.x;
  int w = tid >> 6, lane = tid & 63;
  int lm = lane & 15, lk = lane >> 4;
  int row0 = blockIdx.x * MT;

  for (int it = tid; it < MT * 12; it += NTH) xbuf[it / 12][it % 12] = z[(size_t)row0 * 12 + it];
  for (int it = tid; it < MT * 16; it += NTH) cbuf[it] = (half_t)c[(size_t)row0 * 16 + it];
  for (int it = tid; it < 84; it += NTH) permbuf[it / 12][it % 12] = perms[it];
  if (tid < MT) ldtot[tid] = 0.f;
  __syncthreads();

  for (int l = 0; l < 8; l++) {
    // build MLP input [x1(6) | c(16) | 0(10)] as fp16, A-fragment order (KSA=1):
    // element (m,k) -> inpb[(m>>4)*512 + ((k>>3)*16 + (m&15))*8 + (k&7)]
    for (int it = tid; it < MT * 32; it += NTH) {
      int m = it >> 5, k = it & 31;
      half_t bv;
      if (k < 6)       bv = (half_t)xbuf[m][k];
      else if (k < 22) bv = cbuf[m * 16 + (k - 6)];
      else             bv = (half_t)0.f;
      inpb[(m >> 4) * 512 + ((k >> 3) * 16 + (m & 15)) * 8 + (k & 7)] = bv;
    }
    __syncthreads();
    gemm_elu(inpb, 1, 1,   W0F + (size_t)l * 32 * 512,     1,  b0 + l * 512, hbufA, w, lane, lm, lk);
    __syncthreads();
    gemm_elu(hbufA, 16, 16, W1F + (size_t)l * 512 * 512,  16,  b1 + l * 512, hbufB, w, lane, lm, lk);
    __syncthreads();
    gemm_elu(hbufB, 16, 16, W2F + (size_t)l * 512 * 512,  16,  b2 + l * 512, hbufA, w, lane, lm, lk);
    __syncthreads();
    gemm_out(hbufA, W3F + (size_t)l * 144 * 512, b3 + l * 138, outbuf, w, lane, lm, lk);
    __syncthreads();

    // ---- rational-quadratic spline, one thread per (row, dim) ----
    if (tid < MT * 6) {
      int m = tid / 6, j = tid % 6;
      const float* pr = outbuf + m * OS + j * 23;
      float uw[8], uh[8], dd[9];
#pragma unroll
      for (int i = 0; i < 8; i++) uw[i] = pr[i];
#pragma unroll
      for (int i = 0; i < 8; i++) uh[i] = pr[8 + i];
      dd[0] = 1.f; dd[8] = 1.f;   // MIN_D + softplus(DERIV_CONST) == 1 exactly
#pragma unroll
      for (int i = 0; i < 7; i++) {
        float u = pr[16 + i];
        float sp = (u > 15.f) ? u : log1pf(__expf(u));
        dd[i + 1] = 0.001f + sp;
      }
      float mw = uw[0];
#pragma unroll
      for (int i = 1; i < 8; i++) mw = fmaxf(mw, uw[i]);
      float ew[8], sw = 0.f;
#pragma unroll
      for (int i = 0; i < 8; i++) { ew[i] = __expf(uw[i] - mw); sw += ew[i]; }
      float invw = 1.f / sw;
      float cw[9]; cw[0] = -BND;
      float a = 0.f;
#pragma unroll
      for (int i = 0; i < 8; i++) { a += 0.001f + 0.992f * ew[i] * invw; cw[i + 1] = 2.f * BND * a - BND; }
      cw[8] = BND;
      float mh = uh[0];
#pragma unroll
      for (int i = 1; i < 8; i++) mh = fmaxf(mh, uh[i]);
      float eh[8], sh = 0.f;
#pragma unroll
      for (int i = 0; i < 8; i++) { eh[i] = __expf(uh[i] - mh); sh += eh[i]; }
      float invh = 1.f / sh;
      float ch[9]; ch[0] = -BND;
      float ah = 0.f;
#pragma unroll
      for (int i = 0; i < 8; i++) { ah += 0.001f + 0.992f * eh[i] * invh; ch[i + 1] = 2.f * BND * ah - BND; }
      ch[8] = BND;

      float x2 = xbuf[m][6 + j];
      float xc = fminf(fmaxf(x2, -BND), BND);
      int cnt = 0;
#pragma unroll
      for (int i = 0; i < 9; i++) {
        float edge = (i == 8) ? (cw[8] + 1e-6f) : cw[i];
        cnt += (xc >= edge) ? 1 : 0;
      }
      int idx = cnt - 1; idx = idx < 0 ? 0 : (idx > 7 ? 7 : idx);
      float icw = cw[0], iw = cw[1] - cw[0], ich = ch[0], ih = ch[1] - ch[0], d0 = dd[0], d1 = dd[1];
#pragma unroll
      for (int i = 0; i < 8; i++) {
        if (idx == i) {
          icw = cw[i]; iw = cw[i + 1] - cw[i];
          ich = ch[i]; ih = ch[i + 1] - ch[i];
          d0 = dd[i]; d1 = dd[i + 1];
        }
      }
      float delta = ih / iw;
      float th  = (xc - icw) / iw;
      float t1m = th * (1.f - th);
      float num = ih * (delta * th * th + d0 * t1m);
      float den = delta + (d0 + d1 - 2.f * delta) * t1m;
      float outv = ich + num / den;
      float dnum = delta * delta * (d1 * th * th + 2.f * delta * t1m + d0 * (1.f - th) * (1.f - th));
      float lad = logf(dnum) - 2.f * logf(den);
      bool inside = (x2 >= -BND) && (x2 <= BND);
      xbuf[m][6 + j] = inside ? outv : x2;
      ldpart[m][j]   = inside ? lad : 0.f;
    }
    __syncthreads();
    if (tid < MT) {
      float s = ldtot[tid];
#pragma unroll
      for (int j = 0; j < 6; j++) s += ldpart[tid][j];
      ldtot[tid] = s;
    }
    if (l < 7) {
      // permute xbuf rows: 768 elements over 512 threads
      float v0 = xbuf[tid / 12][permbuf[l][tid % 12]];
      float v1 = 0.f;
      int it1 = tid + NTH;
      if (it1 < MT * 12) v1 = xbuf[it1 / 12][permbuf[l][it1 % 12]];
      __syncthreads();
      xbuf[tid / 12][tid % 12] = v0;
      if (it1 < MT * 12) xbuf[it1 / 12][it1 % 12] = v1;
    }
    __syncthreads();
  }

  for (int it = tid; it < MT * 12; it += NTH) out[(size_t)row0 * 12 + it] = xbuf[it / 12][it % 12];
  if (tid < MT) out[(size_t)NROWS * 12 + row0 + tid] = ldtot[tid];
}

extern "C" void kernel_launch(void* const* d_in, const int* in_sizes, int n_in,
                              void* d_out, int out_size, void* d_ws, size_t ws_size,
                              hipStream_t stream) {
  const float* z  = (const float*)d_in[0];
  const float* c  = (const float*)d_in[1];
  const float* W0 = (const float*)d_in[2];
  const float* b0 = (const float*)d_in[3];
  const float* W1 = (const float*)d_in[4];
  const float* b1 = (const float*)d_in[5];
  const float* W2 = (const float*)d_in[6];
  const float* b2 = (const float*)d_in[7];
  const float* W3 = (const float*)d_in[8];
  const float* b3 = (const float*)d_in[9];
  const int* perms = (const int*)d_in[10];

  unsigned short* wsu = (unsigned short*)d_ws;
  half_t* W0F = (half_t*)(wsu + 0);         // [8][32 frag][512]
  half_t* W1F = (half_t*)(wsu + 131072);    // [8][512 frag][512]
  half_t* W2F = (half_t*)(wsu + 2228224);   // [8][512 frag][512]
  half_t* W3F = (half_t*)(wsu + 4325376);   // [8][144 frag][512]

  // pack: 256 threads = 4 fragments per block
  pack_frag<<<dim3(8,   1, 8), dim3(256), 0, stream>>>(W0, W0F, 22,  512, 32, 1);
  pack_frag<<<dim3(128, 1, 8), dim3(256), 0, stream>>>(W1, W1F, 512, 512, 32, 16);
  pack_frag<<<dim3(128, 1, 8), dim3(256), 0, stream>>>(W2, W2F, 512, 512, 32, 16);
  pack_frag<<<dim3(36,  1, 8), dim3(256), 0, stream>>>(W3, W3F, 512, 138, 9,  16);

  flow_kernel<<<dim3(NROWS / MT), dim3(NTH), 0, stream>>>(
      z, c, b0, b1, b2, b3, perms, W0F, W1F, W2F, W3F, (float*)d_out);
}